// Round 6
// baseline (417.777 us; speedup 1.0000x reference)
//
#include <hip/hip_runtime.h>

#define IN_C   256
#define OUT_C  512
#define WIDTH  56
#define HW     3136        // 56*56
#define KTOT   2304        // IN_C*9
#define NF     64
#define NU     448         // OUT_C - NF
#define NB     32
#define NGRP   8           // ic groups of 32
#define TN     128         // pixels per block (25 tiles, tail tile half)
#define NTILE  25
#define XROWS  242         // TN + 2*57 halo
#define LDX    40          // padded LDS row stride (bf16 elems) = 80 B
#define SLAB   (XROWS * LDX)   // 9680 elems per buffer

typedef __bf16 bf16x8 __attribute__((ext_vector_type(8)));
typedef float  f32x4  __attribute__((ext_vector_type(4)));
typedef float  f32x2  __attribute__((ext_vector_type(2)));

// ---------------- kernel 1: global average pool ----------------
__global__ __launch_bounds__(256) void pool_kernel(const float* __restrict__ x,
                                                   float* __restrict__ pooled) {
    int bc = blockIdx.x;
    const float4* src = (const float4*)(x + (size_t)bc * HW);
    float s = 0.f;
    for (int i = threadIdx.x; i < HW / 4; i += 256) {
        float4 v = src[i];
        s += v.x + v.y + v.z + v.w;
    }
    #pragma unroll
    for (int off = 32; off > 0; off >>= 1) s += __shfl_down(s, off, 64);
    __shared__ float wsum[4];
    int lane = threadIdx.x & 63, wv = threadIdx.x >> 6;
    if (lane == 0) wsum[wv] = s;
    __syncthreads();
    if (threadIdx.x == 0)
        pooled[bc] = (wsum[0] + wsum[1] + wsum[2] + wsum[3]) * (1.0f / HW);
}

// ---------------- kernel 2: router GEMV + top-64 selection ----------------
__global__ __launch_bounds__(512) void router_kernel(const float* __restrict__ pooled,
                                                     const float* __restrict__ rw,
                                                     const float* __restrict__ rb,
                                                     int* __restrict__ sel,
                                                     int* __restrict__ unsel) {
    int b = blockIdx.x;
    __shared__ float p[IN_C];
    __shared__ float v[OUT_C];
    __shared__ int   scount, ucount;
    int t = threadIdx.x;
    if (t < IN_C) p[t] = pooled[b * IN_C + t];
    if (t == 0) { scount = 0; ucount = 0; }
    __syncthreads();
    float acc = rb[t];
    const float* wrow = rw + (size_t)t * IN_C;
    for (int i = 0; i < IN_C; ++i) acc += p[i] * wrow[i];
    v[t] = acc;
    __syncthreads();
    // stable rank: count strictly-greater, plus equal-with-lower-index (matches top_k tie rule)
    int cnt = 0;
    for (int j = 0; j < OUT_C; ++j) {
        float o = v[j];
        cnt += (o > acc) || (o == acc && j < t);
    }
    if (cnt < NF) {
        int pos = atomicAdd(&scount, 1);   // order irrelevant: scatter by oc
        sel[b * NF + pos] = t;
    } else {
        int pos = atomicAdd(&ucount, 1);
        unsel[b * NU + pos] = t;
    }
}

// ---------------- kernel 3: ALL-oc weight compaction (batch-independent, 2.36 MB) ----------------
// Acomp[(g*9+tap)*512 + oc][32 icl] bf16. 72 blocks (one per g,tap), 256 threads x 8 items.
__global__ __launch_bounds__(256) void compact_w(const float* __restrict__ w,
                                                 __bf16* __restrict__ Acomp) {
    int gt = blockIdx.x;
    int g = gt / 9, tap = gt - g * 9;
    int t = threadIdx.x;
    #pragma unroll
    for (int i = 0; i < 8; ++i) {
        int idx = i * 256 + t;
        int oc = idx >> 2, q = idx & 3;
        const float* wsrc = w + (size_t)oc * KTOT + tap;
        bf16x8 o;
        #pragma unroll
        for (int j = 0; j < 8; ++j)
            o[j] = (__bf16)wsrc[(g * 32 + q * 8 + j) * 9];
        *(bf16x8*)&Acomp[((size_t)gt * 512 + oc) * 32 + q * 8] = o;
    }
}

// ---------------- kernel 4: sparse conv — 4-wave blocks, N-split, dbuf slab ----------------
// 800 blocks (25 tiles x 32 batches, XCD-swizzled), 256 threads = 4 waves.
// Wave: M=64 ocs x N=32 px (8 acc frags). K: 8 ic-groups of 32.
// Per group: taps (af from L2-hot Acomp, bfr from LDS slab) -> stage next slab to other
// buffer -> zero-store chunk -> 1 barrier. Boundary masks hoisted to a bitmask; invalid
// frag reads redirect to a zero LDS row (addr cndmask, not data).
__global__ __launch_bounds__(256) void conv_kernel(const float* __restrict__ x,
                                                   const __bf16* __restrict__ Acomp,
                                                   const float* __restrict__ bias,
                                                   const int* __restrict__ sel,
                                                   const int* __restrict__ unsel,
                                                   float* __restrict__ out) {
    // XCD swizzle: each XCD owns 4 batches; Acomp + those batches' x stay L2-hot
    int id   = blockIdx.x;
    int xcd  = id & 7, slot = id >> 3;          // slot in [0,100)
    int bq   = slot / NTILE;
    int tile = slot - bq * NTILE;
    int b    = xcd * 4 + bq;
    int ptile = tile * TN;

    int t    = threadIdx.x;
    int lane = t & 63, wv = t >> 6;
    int fm   = lane & 15, fq = lane >> 4;

    __shared__ __bf16 xlds[2 * SLAB + 32];      // 2 slabs + zero row = 38,784 B

    size_t outb = (size_t)b * OUT_C * HW;
    const float* x_b = x + (size_t)b * IN_C * HW;

    // selected oc per A-frag lane (row index into all-oc Acomp)
    const int* selb = sel + b * NF;
    int selv[4];
    #pragma unroll
    for (int mi = 0; mi < 4; ++mi) selv[mi] = selb[mi * 16 + fm];

    // zerofill oc indices for this wave, preloaded into lanes (readlane later; no per-group vmem)
    const int* ub_all = unsel + b * NU + wv * 112;
    int oc_a = ub_all[lane & 63];
    int oc_b = (lane < 48) ? ub_all[64 + lane] : 0;

    // output px coords + hoisted boundary bitmask (g-invariant)
    int pp[2]; unsigned okb[2] = {0u, 0u};
    #pragma unroll
    for (int s = 0; s < 2; ++s) {
        int p = ptile + wv * 32 + s * 16 + fm;
        pp[s] = p;
        int pc = p < HW ? p : HW - 1;
        int poh = pc / WIDTH, pow_ = pc - (pc / WIDTH) * WIDTH;
        #pragma unroll
        for (int t9 = 0; t9 < 9; ++t9) {
            int r = t9 / 3, c = t9 - 3 * (t9 / 3);
            unsigned ok = ((unsigned)(poh + r - 1) < 56u) && ((unsigned)(pow_ + c - 1) < 56u);
            okb[s] |= ok << t9;
        }
    }

    // staging: wave wv owns rows [wv*61, ...): lanes 0..60 one row each (wave3: 59 rows)
    int  srow = wv * 61 + lane;
    bool sact = (lane < 61) && (srow < XROWS);
    int  gp   = ptile - 57 + srow;
    gp = gp < 0 ? 0 : (gp > HW - 1 ? HW - 1 : gp);
    const float* sx = x_b + gp;

    // zero row init + prologue stage of group 0 into buf 0
    if (t < 32) xlds[2 * SLAB + t] = (__bf16)0.f;
    if (sact) {
        #pragma unroll
        for (int oct = 0; oct < 4; ++oct) {
            float v[8];
            #pragma unroll
            for (int j = 0; j < 8; ++j) v[j] = sx[(size_t)(oct * 8 + j) * HW];
            bf16x8 o;
            #pragma unroll
            for (int j = 0; j < 8; ++j) o[j] = (__bf16)v[j];
            *(bf16x8*)&xlds[srow * LDX + oct * 8] = o;
        }
    }
    __syncthreads();

    f32x4 acc[4][2] = {};
    const int zidx = 2 * SLAB + fq * 8;
    int pxb = ptile + lane * 2;
    bool pok = pxb < HW;

    #pragma unroll 1
    for (int g = 0; g < NGRP; ++g) {
        int bufc = (g & 1) * SLAB;
        int baseS[2];
        #pragma unroll
        for (int s = 0; s < 2; ++s)
            baseS[s] = bufc + (57 + wv * 32 + s * 16 + fm) * LDX + fq * 8;

        // ---- 9 taps from current slab; af loads are the only vmem here ----
        const __bf16* agt = Acomp + (size_t)(g * 9) * 512 * 32;
        #pragma unroll
        for (int t9 = 0; t9 < 9; ++t9) {
            const int r = t9 / 3, c = t9 - 3 * (t9 / 3);
            const int shiftC = ((r - 1) * WIDTH + (c - 1)) * LDX;
            const __bf16* ap = agt + (size_t)t9 * 512 * 32;
            bf16x8 af[4];
            #pragma unroll
            for (int mi = 0; mi < 4; ++mi)
                af[mi] = *(const bf16x8*)(ap + (size_t)selv[mi] * 32 + fq * 8);
            #pragma unroll
            for (int s = 0; s < 2; ++s) {
                int idx = ((okb[s] >> t9) & 1u) ? (baseS[s] + shiftC) : zidx;
                bf16x8 bfr = *(const bf16x8*)&xlds[idx];
                #pragma unroll
                for (int mi = 0; mi < 4; ++mi)
                    acc[mi][s] = __builtin_amdgcn_mfma_f32_16x16x32_bf16(af[mi], bfr, acc[mi][s], 0, 0, 0);
            }
        }

        // ---- stage next group (loads first), then zero-stores, then cvt+write+barrier ----
        if (g < NGRP - 1) {
            float v[32];
            if (sact) {
                const float* sx2 = sx + (size_t)((g + 1) * 32) * HW;
                #pragma unroll
                for (int i = 0; i < 32; ++i) v[i] = sx2[(size_t)i * HW];
            }
            // zero-fill chunk g: 14 planes/wave, uniform oc via readlane (stores sit BEHIND loads)
            #pragma unroll
            for (int i = 0; i < 14; ++i) {
                int j  = g * 14 + i;
                int oc = (j < 64) ? __builtin_amdgcn_readlane(oc_a, j)
                                  : __builtin_amdgcn_readlane(oc_b, j - 64);
                if (pok) {
                    f32x2 z2 = {0.f, 0.f};
                    __builtin_nontemporal_store(z2, (f32x2*)(out + outb + (size_t)oc * HW + pxb));
                }
            }
            if (sact) {
                int dst = (SLAB - bufc) + srow * LDX;   // other buffer
                #pragma unroll
                for (int oct = 0; oct < 4; ++oct) {
                    bf16x8 o;
                    #pragma unroll
                    for (int j = 0; j < 8; ++j) o[j] = (__bf16)v[oct * 8 + j];
                    *(bf16x8*)&xlds[dst + oct * 8] = o;
                }
            }
            __syncthreads();
        } else {
            // last group: final zero-fill chunk only
            #pragma unroll
            for (int i = 0; i < 14; ++i) {
                int j  = g * 14 + i;
                int oc = (j < 64) ? __builtin_amdgcn_readlane(oc_a, j)
                                  : __builtin_amdgcn_readlane(oc_b, j - 64);
                if (pok) {
                    f32x2 z2 = {0.f, 0.f};
                    __builtin_nontemporal_store(z2, (f32x2*)(out + outb + (size_t)oc * HW + pxb));
                }
            }
        }
    }

    // ---- epilogue: bias + masked nontemporal store. C/D: col(lane&15)=px, row=fq*4+reg ----
    #pragma unroll
    for (int mi = 0; mi < 4; ++mi) {
        #pragma unroll
        for (int reg = 0; reg < 4; ++reg) {
            int oc = selb[mi * 16 + fq * 4 + reg];
            float bs = bias[oc];
            float* orow = out + outb + (size_t)oc * HW;
            #pragma unroll
            for (int s = 0; s < 2; ++s)
                if (pp[s] < HW)
                    __builtin_nontemporal_store(acc[mi][s][reg] + bs, &orow[pp[s]]);
        }
    }
}

extern "C" void kernel_launch(void* const* d_in, const int* in_sizes, int n_in,
                              void* d_out, int out_size, void* d_ws, size_t ws_size,
                              hipStream_t stream) {
    (void)in_sizes; (void)n_in; (void)ws_size; (void)out_size;
    const float* x        = (const float*)d_in[0];
    const float* weight   = (const float*)d_in[1];
    const float* bias     = (const float*)d_in[2];
    const float* router_w = (const float*)d_in[3];
    const float* router_b = (const float*)d_in[4];
    float* out = (float*)d_out;

    char* ws = (char*)d_ws;
    float*  pooled = (float*)ws;                       // 32 KB
    int*    sel    = (int*)(ws + 32768);               // 8 KB
    int*    unsel  = (int*)(ws + 40960);               // 56 KB
    __bf16* Acomp  = (__bf16*)(ws + 131072);           // 2.36 MB

    compact_w<<<NGRP * 9, 256, 0, stream>>>(weight, Acomp);   // no deps on router
    pool_kernel<<<NB * IN_C, 256, 0, stream>>>(x, pooled);
    router_kernel<<<NB, OUT_C, 0, stream>>>(pooled, router_w, router_b, sel, unsel);

    conv_kernel<<<NTILE * NB, 256, 0, stream>>>(x, Acomp, bias, sel, unsel, out);
}